// Round 1
// baseline (638.310 us; speedup 1.0000x reference)
//
#include <hip/hip_runtime.h>
#include <hip/hip_bf16.h>

#define NN 50000
#define NE 800000
#define DD 128
#define NCLS 40

// ---------------------------------------------------------------------------
// Detect whether edge_index arrived as int64 (high words all zero) or int32.
__global__ void k_detect(const int* __restrict__ ei, int* __restrict__ flag) {
    __shared__ int nz;
    if (threadIdx.x == 0) nz = 0;
    __syncthreads();
    int any = 0;
    for (int e = threadIdx.x; e < 2048; e += 256)
        if (ei[2 * e + 1] != 0) any = 1;
    if (any) atomicOr(&nz, 1);
    __syncthreads();
    if (threadIdx.x == 0) *flag = (nz == 0) ? 1 : 0;  // 1 => int64 layout
}

__global__ void k_zero_int(int* __restrict__ p, int n) {
    int i = blockIdx.x * 256 + threadIdx.x;
    if (i < n) p[i] = 0;
}

__global__ void k_count(const int* __restrict__ ei, const int* __restrict__ flag,
                        int* __restrict__ cnt) {
    int e = blockIdx.x * 256 + threadIdx.x;
    if (e >= NE) return;
    int is64 = *flag;
    int d = is64 ? ei[2 * (NE + e)] : ei[NE + e];
    atomicAdd(&cnt[d], 1);
}

// Single-block exclusive scan of cnt[0..NN) -> row_ptr[0..NN], zero cursor.
__global__ void k_scan(const int* __restrict__ cnt, int* __restrict__ row_ptr,
                       int* __restrict__ cursor) {
    __shared__ int sums[1024];
    const int CH = 49;  // 1024*49 = 50176 >= 50000
    int t = threadIdx.x;
    int begin = t * CH;
    int end = min(begin + CH, NN);
    int s = 0;
    for (int i = begin; i < end; ++i) s += cnt[i];
    sums[t] = s;
    __syncthreads();
    for (int off = 1; off < 1024; off <<= 1) {
        int v = (t >= off) ? sums[t - off] : 0;
        __syncthreads();
        sums[t] += v;
        __syncthreads();
    }
    int prefix = (t == 0) ? 0 : sums[t - 1];
    for (int i = begin; i < end; ++i) {
        row_ptr[i] = prefix;
        prefix += cnt[i];
        cursor[i] = 0;
    }
    if (t == 1023) row_ptr[NN] = sums[1023];
}

__global__ void k_fill(const int* __restrict__ ei, const int* __restrict__ flag,
                       const int* __restrict__ row_ptr, int* __restrict__ cursor,
                       int* __restrict__ srcs) {
    int e = blockIdx.x * 256 + threadIdx.x;
    if (e >= NE) return;
    int is64 = *flag;
    int s, d;
    if (is64) { s = ei[2 * e]; d = ei[2 * (NE + e)]; }
    else      { s = ei[e];     d = ei[NE + e]; }
    int pos = row_ptr[d] + atomicAdd(&cursor[d], 1);
    srcs[pos] = s;
}

// ---------------------------------------------------------------------------
// Pull-based mean aggregation: one 128-thread block per node, feature/thread.
__global__ void k_agg(const float* __restrict__ in, const int* __restrict__ row_ptr,
                      const int* __restrict__ srcs, float* __restrict__ agg) {
    int n = blockIdx.x;
    int f = threadIdx.x;  // 0..127
    int b = row_ptr[n], e = row_ptr[n + 1];
    float acc = 0.0f;
    int i = b;
    for (; i + 3 < e; i += 4) {
        int s0 = srcs[i + 0], s1 = srcs[i + 1], s2 = srcs[i + 2], s3 = srcs[i + 3];
        acc += in[(size_t)s0 * DD + f];
        acc += in[(size_t)s1 * DD + f];
        acc += in[(size_t)s2 * DD + f];
        acc += in[(size_t)s3 * DD + f];
    }
    for (; i < e; ++i) acc += in[(size_t)srcs[i] * DD + f];
    int deg = e - b;
    float inv = 1.0f / (float)(deg > 0 ? deg : 1);
    agg[(size_t)n * DD + f] = acc * inv;
}

// ---------------------------------------------------------------------------
// out[m,n] = relu( sum_k agg[m,k]*Wl[k,n] + in[m,k]*Wr[k,n] + bias[n] )
// K=256 (concat), BM=BN=64, BK=32, 256 threads, 4x4 acc per thread.
__global__ void k_gemm(const float* __restrict__ A1,  // agg   [NN,128]
                       const float* __restrict__ A2,  // in    [NN,128]
                       const float* __restrict__ Wl,  // [128,ncols]
                       const float* __restrict__ Wr,  // [128,ncols]
                       const float* __restrict__ bias,
                       float* __restrict__ out, const int ncols) {
    __shared__ float As[32][68];  // [k][m], padded (68*4B rows keep 16B align)
    __shared__ float Bs[32][68];  // [k][n]
    int tid = threadIdx.x;
    int tm = tid & 15, tn = tid >> 4;
    int m0 = blockIdx.x * 64;
    int n0 = blockIdx.y * 64;
    float acc[4][4] = {};

    for (int kt = 0; kt < 8; ++kt) {
        int kbase = kt * 32;
        // ---- stage A tile (64 rows x 32 k) as float4, store transposed
#pragma unroll
        for (int i = 0; i < 2; ++i) {
            int l = tid + i * 256;       // 0..511
            int r = l >> 3;              // 0..63 row
            int c4 = l & 7;              // float4 col within 32-wide slice
            int gm = m0 + r;
            int gk = kbase + c4 * 4;
            float4 v = make_float4(0.f, 0.f, 0.f, 0.f);
            if (gm < NN) {
                const float* src = (gk < 128) ? (A1 + (size_t)gm * 128 + gk)
                                              : (A2 + (size_t)gm * 128 + (gk - 128));
                v = *(const float4*)src;
            }
            As[c4 * 4 + 0][r] = v.x;
            As[c4 * 4 + 1][r] = v.y;
            As[c4 * 4 + 2][r] = v.z;
            As[c4 * 4 + 3][r] = v.w;
        }
        // ---- stage B tile (32 k x 64 n)
#pragma unroll
        for (int i = 0; i < 8; ++i) {
            int l = tid + i * 256;  // 0..2047
            int kk = l >> 6;        // 0..31
            int n = l & 63;         // 0..63
            int gk = kbase + kk;
            int gn = n0 + n;
            float v = 0.f;
            if (gn < ncols)
                v = (gk < 128) ? Wl[(size_t)gk * ncols + gn]
                               : Wr[(size_t)(gk - 128) * ncols + gn];
            Bs[kk][n] = v;
        }
        __syncthreads();
#pragma unroll
        for (int k = 0; k < 32; ++k) {
            float4 a = *(const float4*)&As[k][tm * 4];
            float4 b = *(const float4*)&Bs[k][tn * 4];
            float av[4] = {a.x, a.y, a.z, a.w};
            float bv[4] = {b.x, b.y, b.z, b.w};
#pragma unroll
            for (int ii = 0; ii < 4; ++ii)
#pragma unroll
                for (int jj = 0; jj < 4; ++jj) acc[ii][jj] += av[ii] * bv[jj];
        }
        __syncthreads();
    }
    // ---- epilogue: bias + relu
#pragma unroll
    for (int i = 0; i < 4; ++i) {
        int gm = m0 + tm * 4 + i;
        if (gm >= NN) continue;
#pragma unroll
        for (int j = 0; j < 4; ++j) {
            int gn = n0 + tn * 4 + j;
            if (gn < ncols) {
                float v = acc[i][j] + bias[gn];
                out[(size_t)gm * ncols + gn] = v > 0.f ? v : 0.f;
            }
        }
    }
}

// ---------------------------------------------------------------------------
extern "C" void kernel_launch(void* const* d_in, const int* in_sizes, int n_in,
                              void* d_out, int out_size, void* d_ws, size_t ws_size,
                              hipStream_t stream) {
    const float* x    = (const float*)d_in[0];
    const int*   ei   = (const int*)d_in[1];
    const float* w1_l = (const float*)d_in[2];
    const float* w1_r = (const float*)d_in[3];
    const float* b1   = (const float*)d_in[4];
    const float* w2_l = (const float*)d_in[5];
    const float* w2_r = (const float*)d_in[6];
    const float* b2   = (const float*)d_in[7];
    const float* w3_l = (const float*)d_in[8];
    const float* w3_r = (const float*)d_in[9];
    const float* b3   = (const float*)d_in[10];
    float* out = (float*)d_out;

    char* w = (char*)d_ws;
    size_t off = 0;
    auto alloc = [&](size_t bytes) -> void* {
        void* p = w + off;
        off += (bytes + 255) / 256 * 256;
        return p;
    };
    int*   flag    = (int*)alloc(4);
    int*   cnt     = (int*)alloc((size_t)NN * 4);
    int*   row_ptr = (int*)alloc((size_t)(NN + 1) * 4);
    int*   cursor  = (int*)alloc((size_t)NN * 4);
    int*   srcs    = (int*)alloc((size_t)NE * 4);
    float* agg     = (float*)alloc((size_t)NN * DD * 4);
    float* h1      = (float*)alloc((size_t)NN * DD * 4);
    float* h2      = (float*)alloc((size_t)NN * DD * 4);
    (void)ws_size;

    const int eb = (NE + 255) / 256;
    k_zero_int<<<(NN + 255) / 256, 256, 0, stream>>>(cnt, NN);
    k_detect<<<1, 256, 0, stream>>>(ei, flag);
    k_count<<<eb, 256, 0, stream>>>(ei, flag, cnt);
    k_scan<<<1, 1024, 0, stream>>>(cnt, row_ptr, cursor);
    k_fill<<<eb, 256, 0, stream>>>(ei, flag, row_ptr, cursor, srcs);

    const int gm = (NN + 63) / 64;  // 782
    // Layer 1
    k_agg<<<NN, DD, 0, stream>>>(x, row_ptr, srcs, agg);
    k_gemm<<<dim3(gm, 2), 256, 0, stream>>>(agg, x, w1_l, w1_r, b1, h1, DD);
    // Layer 2
    k_agg<<<NN, DD, 0, stream>>>(h1, row_ptr, srcs, agg);
    k_gemm<<<dim3(gm, 2), 256, 0, stream>>>(agg, h1, w2_l, w2_r, b2, h2, DD);
    // Layer 3
    k_agg<<<NN, DD, 0, stream>>>(h2, row_ptr, srcs, agg);
    k_gemm<<<dim3(gm, 1), 256, 0, stream>>>(agg, h2, w3_l, w3_r, b3, out, NCLS);
}

// Round 2
// 529.120 us; speedup vs baseline: 1.2064x; 1.2064x over previous
//
#include <hip/hip_runtime.h>
#include <hip/hip_bf16.h>

#define NN 50000
#define NE 800000
#define DD 128
#define NCLS 40

// ---------------------------------------------------------------------------
// Detect whether edge_index arrived as int64 (high words all zero) or int32.
__global__ void k_detect(const int* __restrict__ ei, int* __restrict__ flag) {
    __shared__ int nz;
    if (threadIdx.x == 0) nz = 0;
    __syncthreads();
    int any = 0;
    for (int e = threadIdx.x; e < 2048; e += 256)
        if (ei[2 * e + 1] != 0) any = 1;
    if (any) atomicOr(&nz, 1);
    __syncthreads();
    if (threadIdx.x == 0) *flag = (nz == 0) ? 1 : 0;  // 1 => int64 layout
}

__global__ void k_zero_int(int* __restrict__ p, int n) {
    int i = blockIdx.x * 256 + threadIdx.x;
    if (i < n) p[i] = 0;
}

__global__ void k_count(const int* __restrict__ ei, const int* __restrict__ flag,
                        int* __restrict__ cnt) {
    int e = blockIdx.x * 256 + threadIdx.x;
    if (e >= NE) return;
    int is64 = *flag;
    int d = is64 ? ei[2 * (NE + e)] : ei[NE + e];
    atomicAdd(&cnt[d], 1);
}

// ---------------------------------------------------------------------------
// Two-level scan: 49 blocks x 1024 -> inclusive partials + block sums.
__global__ void k_scan1(const int* __restrict__ cnt, int* __restrict__ incl,
                        int* __restrict__ bsum) {
    __shared__ int s[1024];
    int t = threadIdx.x;
    int i = blockIdx.x * 1024 + t;
    int v = (i < NN) ? cnt[i] : 0;
    s[t] = v;
    __syncthreads();
#pragma unroll
    for (int off = 1; off < 1024; off <<= 1) {
        int u = (t >= off) ? s[t - off] : 0;
        __syncthreads();
        s[t] += u;
        __syncthreads();
    }
    if (i < NN) incl[i] = s[t];
    if (t == 1023) bsum[blockIdx.x] = s[1023];
}

// Exclusive scan of 49 block sums (single small block).
__global__ void k_scan2(int* __restrict__ bsum, int* __restrict__ boff,
                        const int nb) {
    __shared__ int s[64];
    int t = threadIdx.x;
    s[t] = (t < nb) ? bsum[t] : 0;
    __syncthreads();
#pragma unroll
    for (int off = 1; off < 64; off <<= 1) {
        int u = (t >= off) ? s[t - off] : 0;
        __syncthreads();
        s[t] += u;
        __syncthreads();
    }
    if (t < nb) boff[t] = s[t] - bsum[t];     // exclusive
    if (t == 63) boff[nb] = s[63];            // grand total
}

// row_ptr[i] = incl[i] - cnt[i] + boff[block]; zero cursor.
__global__ void k_scan3(const int* __restrict__ cnt, const int* __restrict__ incl,
                        const int* __restrict__ boff, int* __restrict__ row_ptr,
                        int* __restrict__ cursor, const int nb) {
    int i = blockIdx.x * 1024 + threadIdx.x;
    if (i < NN) {
        row_ptr[i] = incl[i] - cnt[i] + boff[blockIdx.x];
        cursor[i] = 0;
    }
    if (i == 0) row_ptr[NN] = boff[nb];
}

__global__ void k_fill(const int* __restrict__ ei, const int* __restrict__ flag,
                       const int* __restrict__ row_ptr, int* __restrict__ cursor,
                       int* __restrict__ srcs) {
    int e = blockIdx.x * 256 + threadIdx.x;
    if (e >= NE) return;
    int is64 = *flag;
    int s, d;
    if (is64) { s = ei[2 * e]; d = ei[2 * (NE + e)]; }
    else      { s = ei[e];     d = ei[NE + e]; }
    int pos = row_ptr[d] + atomicAdd(&cursor[d], 1);
    srcs[pos] = s;
}

// ---------------------------------------------------------------------------
// Pull-based mean aggregation: one 128-thread block per node, feature/thread.
__global__ void k_agg(const float* __restrict__ in, const int* __restrict__ row_ptr,
                      const int* __restrict__ srcs, float* __restrict__ agg) {
    int n = blockIdx.x;
    int f = threadIdx.x;  // 0..127
    int b = row_ptr[n], e = row_ptr[n + 1];
    float acc = 0.0f;
    int i = b;
    for (; i + 3 < e; i += 4) {
        int s0 = srcs[i + 0], s1 = srcs[i + 1], s2 = srcs[i + 2], s3 = srcs[i + 3];
        acc += in[(size_t)s0 * DD + f];
        acc += in[(size_t)s1 * DD + f];
        acc += in[(size_t)s2 * DD + f];
        acc += in[(size_t)s3 * DD + f];
    }
    for (; i < e; ++i) acc += in[(size_t)srcs[i] * DD + f];
    int deg = e - b;
    float inv = 1.0f / (float)(deg > 0 ? deg : 1);
    agg[(size_t)n * DD + f] = acc * inv;
}

// ---------------------------------------------------------------------------
// out[m,n] = relu( sum_k agg[m,k]*Wl[k,n] + in[m,k]*Wr[k,n] + bias[n] )
// K=256 (concat), BM=BN=64, BK=32, 256 threads, 4x4 acc per thread.
__global__ void k_gemm(const float* __restrict__ A1,  // agg   [NN,128]
                       const float* __restrict__ A2,  // in    [NN,128]
                       const float* __restrict__ Wl,  // [128,ncols]
                       const float* __restrict__ Wr,  // [128,ncols]
                       const float* __restrict__ bias,
                       float* __restrict__ out, const int ncols) {
    __shared__ float As[32][68];  // [k][m], padded
    __shared__ float Bs[32][68];  // [k][n]
    int tid = threadIdx.x;
    int tm = tid & 15, tn = tid >> 4;
    int m0 = blockIdx.x * 64;
    int n0 = blockIdx.y * 64;
    float acc[4][4] = {};

    for (int kt = 0; kt < 8; ++kt) {
        int kbase = kt * 32;
#pragma unroll
        for (int i = 0; i < 2; ++i) {
            int l = tid + i * 256;       // 0..511
            int r = l >> 3;              // 0..63 row
            int c4 = l & 7;              // float4 col within 32-wide slice
            int gm = m0 + r;
            int gk = kbase + c4 * 4;
            float4 v = make_float4(0.f, 0.f, 0.f, 0.f);
            if (gm < NN) {
                const float* src = (gk < 128) ? (A1 + (size_t)gm * 128 + gk)
                                              : (A2 + (size_t)gm * 128 + (gk - 128));
                v = *(const float4*)src;
            }
            As[c4 * 4 + 0][r] = v.x;
            As[c4 * 4 + 1][r] = v.y;
            As[c4 * 4 + 2][r] = v.z;
            As[c4 * 4 + 3][r] = v.w;
        }
#pragma unroll
        for (int i = 0; i < 8; ++i) {
            int l = tid + i * 256;  // 0..2047
            int kk = l >> 6;        // 0..31
            int n = l & 63;         // 0..63
            int gk = kbase + kk;
            int gn = n0 + n;
            float v = 0.f;
            if (gn < ncols)
                v = (gk < 128) ? Wl[(size_t)gk * ncols + gn]
                               : Wr[(size_t)(gk - 128) * ncols + gn];
            Bs[kk][n] = v;
        }
        __syncthreads();
#pragma unroll
        for (int k = 0; k < 32; ++k) {
            float4 a = *(const float4*)&As[k][tm * 4];
            float4 b = *(const float4*)&Bs[k][tn * 4];
            float av[4] = {a.x, a.y, a.z, a.w};
            float bv[4] = {b.x, b.y, b.z, b.w};
#pragma unroll
            for (int ii = 0; ii < 4; ++ii)
#pragma unroll
                for (int jj = 0; jj < 4; ++jj) acc[ii][jj] += av[ii] * bv[jj];
        }
        __syncthreads();
    }
#pragma unroll
    for (int i = 0; i < 4; ++i) {
        int gm = m0 + tm * 4 + i;
        if (gm >= NN) continue;
#pragma unroll
        for (int j = 0; j < 4; ++j) {
            int gn = n0 + tn * 4 + j;
            if (gn < ncols) {
                float v = acc[i][j] + bias[gn];
                out[(size_t)gm * ncols + gn] = v > 0.f ? v : 0.f;
            }
        }
    }
}

// ---------------------------------------------------------------------------
extern "C" void kernel_launch(void* const* d_in, const int* in_sizes, int n_in,
                              void* d_out, int out_size, void* d_ws, size_t ws_size,
                              hipStream_t stream) {
    const float* x    = (const float*)d_in[0];
    const int*   ei   = (const int*)d_in[1];
    const float* w1_l = (const float*)d_in[2];
    const float* w1_r = (const float*)d_in[3];
    const float* b1   = (const float*)d_in[4];
    const float* w2_l = (const float*)d_in[5];
    const float* w2_r = (const float*)d_in[6];
    const float* b2   = (const float*)d_in[7];
    const float* w3_l = (const float*)d_in[8];
    const float* w3_r = (const float*)d_in[9];
    const float* b3   = (const float*)d_in[10];
    float* out = (float*)d_out;

    char* w = (char*)d_ws;
    size_t off = 0;
    auto alloc = [&](size_t bytes) -> void* {
        void* p = w + off;
        off += (bytes + 255) / 256 * 256;
        return p;
    };
    int*   flag    = (int*)alloc(4);
    int*   cnt     = (int*)alloc((size_t)NN * 4);
    int*   row_ptr = (int*)alloc((size_t)(NN + 1) * 4);
    int*   cursor  = (int*)alloc((size_t)NN * 4);
    int*   srcs    = (int*)alloc((size_t)NE * 4);
    int*   incl    = (int*)alloc((size_t)NN * 4);
    int*   bsum    = (int*)alloc(64 * 4);
    int*   boff    = (int*)alloc(64 * 4);
    float* agg     = (float*)alloc((size_t)NN * DD * 4);
    float* h1      = (float*)alloc((size_t)NN * DD * 4);
    float* h2      = (float*)alloc((size_t)NN * DD * 4);
    (void)ws_size;

    const int eb = (NE + 255) / 256;
    const int nb = (NN + 1023) / 1024;  // 49
    k_zero_int<<<(NN + 255) / 256, 256, 0, stream>>>(cnt, NN);
    k_detect<<<1, 256, 0, stream>>>(ei, flag);
    k_count<<<eb, 256, 0, stream>>>(ei, flag, cnt);
    k_scan1<<<nb, 1024, 0, stream>>>(cnt, incl, bsum);
    k_scan2<<<1, 64, 0, stream>>>(bsum, boff, nb);
    k_scan3<<<nb, 1024, 0, stream>>>(cnt, incl, boff, row_ptr, cursor, nb);
    k_fill<<<eb, 256, 0, stream>>>(ei, flag, row_ptr, cursor, srcs);

    const int gm = (NN + 63) / 64;  // 782
    // Layer 1
    k_agg<<<NN, DD, 0, stream>>>(x, row_ptr, srcs, agg);
    k_gemm<<<dim3(gm, 2), 256, 0, stream>>>(agg, x, w1_l, w1_r, b1, h1, DD);
    // Layer 2
    k_agg<<<NN, DD, 0, stream>>>(h1, row_ptr, srcs, agg);
    k_gemm<<<dim3(gm, 2), 256, 0, stream>>>(agg, h1, w2_l, w2_r, b2, h2, DD);
    // Layer 3
    k_agg<<<NN, DD, 0, stream>>>(h2, row_ptr, srcs, agg);
    k_gemm<<<dim3(gm, 1), 256, 0, stream>>>(agg, h2, w3_l, w3_r, b3, out, NCLS);
}

// Round 3
// 487.526 us; speedup vs baseline: 1.3093x; 1.0853x over previous
//
#include <hip/hip_runtime.h>
#include <hip/hip_bf16.h>

#define NN 50000
#define NE 800000
#define DD 128
#define NCLS 40

typedef short bf8 __attribute__((ext_vector_type(8)));   // 8 bf16 (4 VGPRs)
typedef float f32x4 __attribute__((ext_vector_type(4))); // MFMA acc

__device__ __forceinline__ unsigned short f2bf(float x) {
    unsigned int u = __float_as_uint(x);
    unsigned int r = (u + 0x7FFFu + ((u >> 16) & 1u)) >> 16;  // RNE
    return (unsigned short)r;
}
__device__ __forceinline__ float bf2f(unsigned short h) {
    return __uint_as_float(((unsigned int)h) << 16);
}

// ---------------------------------------------------------------------------
__global__ void k_detect(const int* __restrict__ ei, int* __restrict__ flag) {
    __shared__ int nz;
    if (threadIdx.x == 0) nz = 0;
    __syncthreads();
    int any = 0;
    for (int e = threadIdx.x; e < 2048; e += 256)
        if (ei[2 * e + 1] != 0) any = 1;
    if (any) atomicOr(&nz, 1);
    __syncthreads();
    if (threadIdx.x == 0) *flag = (nz == 0) ? 1 : 0;  // 1 => int64 layout
}

__global__ void k_zero_int(int* __restrict__ p, int n) {
    int i = blockIdx.x * 256 + threadIdx.x;
    if (i < n) p[i] = 0;
}

__global__ void k_count(const int* __restrict__ ei, const int* __restrict__ flag,
                        int* __restrict__ cnt) {
    int e = blockIdx.x * 256 + threadIdx.x;
    if (e >= NE) return;
    int is64 = *flag;
    int d = is64 ? ei[2 * (NE + e)] : ei[NE + e];
    atomicAdd(&cnt[d], 1);
}

__global__ void k_scan1(const int* __restrict__ cnt, int* __restrict__ incl,
                        int* __restrict__ bsum) {
    __shared__ int s[1024];
    int t = threadIdx.x;
    int i = blockIdx.x * 1024 + t;
    int v = (i < NN) ? cnt[i] : 0;
    s[t] = v;
    __syncthreads();
#pragma unroll
    for (int off = 1; off < 1024; off <<= 1) {
        int u = (t >= off) ? s[t - off] : 0;
        __syncthreads();
        s[t] += u;
        __syncthreads();
    }
    if (i < NN) incl[i] = s[t];
    if (t == 1023) bsum[blockIdx.x] = s[1023];
}

__global__ void k_scan2(int* __restrict__ bsum, int* __restrict__ boff,
                        const int nb) {
    __shared__ int s[64];
    int t = threadIdx.x;
    s[t] = (t < nb) ? bsum[t] : 0;
    __syncthreads();
#pragma unroll
    for (int off = 1; off < 64; off <<= 1) {
        int u = (t >= off) ? s[t - off] : 0;
        __syncthreads();
        s[t] += u;
        __syncthreads();
    }
    if (t < nb) boff[t] = s[t] - bsum[t];
    if (t == 63) boff[nb] = s[63];
}

__global__ void k_scan3(const int* __restrict__ cnt, const int* __restrict__ incl,
                        const int* __restrict__ boff, int* __restrict__ row_ptr,
                        int* __restrict__ cursor, const int nb) {
    int i = blockIdx.x * 1024 + threadIdx.x;
    if (i < NN) {
        row_ptr[i] = incl[i] - cnt[i] + boff[blockIdx.x];
        cursor[i] = 0;
    }
    if (i == 0) row_ptr[NN] = boff[nb];
}

__global__ void k_fill(const int* __restrict__ ei, const int* __restrict__ flag,
                       const int* __restrict__ row_ptr, int* __restrict__ cursor,
                       int* __restrict__ srcs) {
    int e = blockIdx.x * 256 + threadIdx.x;
    if (e >= NE) return;
    int is64 = *flag;
    int s, d;
    if (is64) { s = ei[2 * e]; d = ei[2 * (NE + e)]; }
    else      { s = ei[e];     d = ei[NE + e]; }
    int pos = row_ptr[d] + atomicAdd(&cursor[d], 1);
    srcs[pos] = s;
}

// ---------------------------------------------------------------------------
// fp32 -> (hi,lo) bf16 split, elementwise. 50000*128/4 = 1.6M float4.
__global__ void k_cvt_x(const float* __restrict__ x, unsigned short* __restrict__ xh,
                        unsigned short* __restrict__ xl) {
    int i = blockIdx.x * 256 + threadIdx.x;  // float4 index, grid covers exactly
    float4 v = ((const float4*)x)[i];
    unsigned short h[4], l[4];
    float f[4] = {v.x, v.y, v.z, v.w};
#pragma unroll
    for (int j = 0; j < 4; ++j) {
        h[j] = f2bf(f[j]);
        l[j] = f2bf(f[j] - bf2f(h[j]));
    }
    ((ushort4*)xh)[i] = make_ushort4(h[0], h[1], h[2], h[3]);
    ((ushort4*)xl)[i] = make_ushort4(l[0], l[1], l[2], l[3]);
}

// Build Bt[n][k] (n-major, k=0..255 over [Wl;Wr]), hi/lo split, zero pad n>=NC.
// grid.x = 128 (n), 256 threads (k).
__global__ void k_cvt_w(const float* __restrict__ wl, const float* __restrict__ wr,
                        unsigned short* __restrict__ bth, unsigned short* __restrict__ btl,
                        const int NC) {
    int n = blockIdx.x;
    int k = threadIdx.x;
    float v = 0.f;
    if (n < NC)
        v = (k < 128) ? wl[(size_t)k * NC + n] : wr[(size_t)(k - 128) * NC + n];
    unsigned short h = f2bf(v);
    unsigned short l = f2bf(v - bf2f(h));
    bth[(size_t)n * 256 + k] = h;
    btl[(size_t)n * 256 + k] = l;
}

// ---------------------------------------------------------------------------
// Pull-based mean aggregation: fp32 gather in, (hi,lo) bf16 out.
__global__ void k_agg(const float* __restrict__ in, const int* __restrict__ row_ptr,
                      const int* __restrict__ srcs, unsigned short* __restrict__ oh,
                      unsigned short* __restrict__ ol) {
    int n = blockIdx.x;
    int f = threadIdx.x;  // 0..127
    int b = row_ptr[n], e = row_ptr[n + 1];
    float acc = 0.0f;
    int i = b;
    for (; i + 3 < e; i += 4) {
        int s0 = srcs[i + 0], s1 = srcs[i + 1], s2 = srcs[i + 2], s3 = srcs[i + 3];
        acc += in[(size_t)s0 * DD + f];
        acc += in[(size_t)s1 * DD + f];
        acc += in[(size_t)s2 * DD + f];
        acc += in[(size_t)s3 * DD + f];
    }
    for (; i < e; ++i) acc += in[(size_t)srcs[i] * DD + f];
    int deg = e - b;
    float inv = 1.0f / (float)(deg > 0 ? deg : 1);
    float v = acc * inv;
    unsigned short h = f2bf(v);
    oh[(size_t)n * DD + f] = h;
    ol[(size_t)n * DD + f] = f2bf(v - bf2f(h));
}

// ---------------------------------------------------------------------------
// Split-precision bf16 MFMA GEMM: C = relu([A1|A2] @ Bt^T + bias)
//   A1,A2: [NN,128] hi/lo bf16 (K-concat: k<128 -> A1, else A2)
//   Bt:    [128,256] hi/lo bf16, n-major (zero-padded rows n>=NC)
// 256 thr = 4 waves; wave covers 2 m-tiles (32 rows); block = 128 rows.
// 3-product split: Ah*Bh + Al*Bh + Ah*Bl (lo*lo dropped, ~2^-16 rel).
template <int NT, bool BF16OUT>
__global__ void k_mfma(const unsigned short* __restrict__ A1h, const unsigned short* __restrict__ A1l,
                       const unsigned short* __restrict__ A2h, const unsigned short* __restrict__ A2l,
                       const unsigned short* __restrict__ Bth, const unsigned short* __restrict__ Btl,
                       const float* __restrict__ bias, float* __restrict__ outf,
                       unsigned short* __restrict__ outh, unsigned short* __restrict__ outl,
                       const int NC) {
    const int tid = threadIdx.x;
    const int wave = tid >> 6, lane = tid & 63;
    const int quad = lane >> 4, mr = lane & 15;
    const int m0 = blockIdx.x * 128 + wave * 32;

    f32x4 acc[2][NT] = {};
    const bf8 zero = {};

#pragma unroll
    for (int ks = 0; ks < 8; ++ks) {
        const int kb = ks * 32;
        const unsigned short* baseh = (kb < 128) ? A1h : A2h;
        const unsigned short* basel = (kb < 128) ? A1l : A2l;
        const int ko = (kb < 128 ? kb : kb - 128) + quad * 8;
        bf8 ah[2], al[2];
#pragma unroll
        for (int t = 0; t < 2; ++t) {
            int row = m0 + t * 16 + mr;
            size_t off = (size_t)row * 128 + ko;
            bool ok = row < NN;
            ah[t] = ok ? *(const bf8*)(baseh + off) : zero;
            al[t] = ok ? *(const bf8*)(basel + off) : zero;
        }
#pragma unroll
        for (int n = 0; n < NT; ++n) {
            size_t boff = (size_t)(n * 16 + mr) * 256 + kb + quad * 8;
            bf8 bh = *(const bf8*)(Bth + boff);
            bf8 bl = *(const bf8*)(Btl + boff);
#pragma unroll
            for (int t = 0; t < 2; ++t) {
                acc[t][n] = __builtin_amdgcn_mfma_f32_16x16x32_bf16(ah[t], bh, acc[t][n], 0, 0, 0);
                acc[t][n] = __builtin_amdgcn_mfma_f32_16x16x32_bf16(al[t], bh, acc[t][n], 0, 0, 0);
                acc[t][n] = __builtin_amdgcn_mfma_f32_16x16x32_bf16(ah[t], bl, acc[t][n], 0, 0, 0);
            }
        }
    }

    // Epilogue. C/D layout: col = lane&15, row = quad*4 + reg.
#pragma unroll
    for (int t = 0; t < 2; ++t) {
#pragma unroll
        for (int n = 0; n < NT; ++n) {
            int col = n * 16 + mr;
            float bv = (col < NC) ? bias[col] : 0.f;
#pragma unroll
            for (int r = 0; r < 4; ++r) {
                int row = m0 + t * 16 + quad * 4 + r;
                if (row < NN && col < NC) {
                    float v = acc[t][n][r] + bv;
                    v = v > 0.f ? v : 0.f;
                    if (BF16OUT) {
                        outf[(size_t)row * NC + col] = v;
                        unsigned short h = f2bf(v);
                        outh[(size_t)row * 128 + col] = h;
                        outl[(size_t)row * 128 + col] = f2bf(v - bf2f(h));
                    } else {
                        outf[(size_t)row * NC + col] = v;
                    }
                }
            }
        }
    }
}

// ---------------------------------------------------------------------------
extern "C" void kernel_launch(void* const* d_in, const int* in_sizes, int n_in,
                              void* d_out, int out_size, void* d_ws, size_t ws_size,
                              hipStream_t stream) {
    const float* x    = (const float*)d_in[0];
    const int*   ei   = (const int*)d_in[1];
    const float* w1_l = (const float*)d_in[2];
    const float* w1_r = (const float*)d_in[3];
    const float* b1   = (const float*)d_in[4];
    const float* w2_l = (const float*)d_in[5];
    const float* w2_r = (const float*)d_in[6];
    const float* b2   = (const float*)d_in[7];
    const float* w3_l = (const float*)d_in[8];
    const float* w3_r = (const float*)d_in[9];
    const float* b3   = (const float*)d_in[10];
    float* out = (float*)d_out;

    char* w = (char*)d_ws;
    size_t off = 0;
    auto alloc = [&](size_t bytes) -> void* {
        void* p = w + off;
        off += (bytes + 255) / 256 * 256;
        return p;
    };
    int* flag    = (int*)alloc(4);
    int* cnt     = (int*)alloc((size_t)NN * 4);
    int* row_ptr = (int*)alloc((size_t)(NN + 1) * 4);
    int* cursor  = (int*)alloc((size_t)NN * 4);
    int* srcs    = (int*)alloc((size_t)NE * 4);
    int* incl    = (int*)alloc((size_t)NN * 4);
    int* bsum    = (int*)alloc(64 * 4);
    int* boff    = (int*)alloc(64 * 4);
    unsigned short* xh   = (unsigned short*)alloc((size_t)NN * DD * 2);  // also h2h
    unsigned short* xl   = (unsigned short*)alloc((size_t)NN * DD * 2);  // also h2l
    unsigned short* aggh = (unsigned short*)alloc((size_t)NN * DD * 2);
    unsigned short* aggl = (unsigned short*)alloc((size_t)NN * DD * 2);
    unsigned short* h1h  = (unsigned short*)alloc((size_t)NN * DD * 2);
    unsigned short* h1l  = (unsigned short*)alloc((size_t)NN * DD * 2);
    float* h1f           = (float*)alloc((size_t)NN * DD * 4);           // also h2f
    unsigned short* bt1h = (unsigned short*)alloc(128 * 256 * 2);
    unsigned short* bt1l = (unsigned short*)alloc(128 * 256 * 2);
    unsigned short* bt2h = (unsigned short*)alloc(128 * 256 * 2);
    unsigned short* bt2l = (unsigned short*)alloc(128 * 256 * 2);
    unsigned short* bt3h = (unsigned short*)alloc(128 * 256 * 2);
    unsigned short* bt3l = (unsigned short*)alloc(128 * 256 * 2);
    unsigned short* h2h = xh, *h2l = xl;  // x dead after layer-1 GEMM
    float* h2f = h1f;                     // h1f dead after layer-2 agg
    (void)ws_size;

    const int eb = (NE + 255) / 256;
    const int nb = (NN + 1023) / 1024;  // 49
    k_zero_int<<<(NN + 255) / 256, 256, 0, stream>>>(cnt, NN);
    k_detect<<<1, 256, 0, stream>>>(ei, flag);
    k_count<<<eb, 256, 0, stream>>>(ei, flag, cnt);
    k_scan1<<<nb, 1024, 0, stream>>>(cnt, incl, bsum);
    k_scan2<<<1, 64, 0, stream>>>(bsum, boff, nb);
    k_scan3<<<nb, 1024, 0, stream>>>(cnt, incl, boff, row_ptr, cursor, nb);
    k_fill<<<eb, 256, 0, stream>>>(ei, flag, row_ptr, cursor, srcs);

    k_cvt_x<<<(NN * DD / 4) / 256, 256, 0, stream>>>(x, xh, xl);
    k_cvt_w<<<128, 256, 0, stream>>>(w1_l, w1_r, bt1h, bt1l, DD);
    k_cvt_w<<<128, 256, 0, stream>>>(w2_l, w2_r, bt2h, bt2l, DD);
    k_cvt_w<<<128, 256, 0, stream>>>(w3_l, w3_r, bt3h, bt3l, NCLS);

    const int gmb = (NN + 127) / 128;  // 391
    // Layer 1
    k_agg<<<NN, DD, 0, stream>>>(x, row_ptr, srcs, aggh, aggl);
    k_mfma<8, true><<<gmb, 256, 0, stream>>>(aggh, aggl, xh, xl, bt1h, bt1l, b1,
                                             h1f, h1h, h1l, DD);
    // Layer 2 (writes h2 into x's buffers + h1f buffer; h1h/h1l are A2)
    k_agg<<<NN, DD, 0, stream>>>(h1f, row_ptr, srcs, aggh, aggl);
    k_mfma<8, true><<<gmb, 256, 0, stream>>>(aggh, aggl, h1h, h1l, bt2h, bt2l, b2,
                                             h2f, h2h, h2l, DD);
    // Layer 3
    k_agg<<<NN, DD, 0, stream>>>(h2f, row_ptr, srcs, aggh, aggl);
    k_mfma<3, false><<<gmb, 256, 0, stream>>>(aggh, aggl, h2h, h2l, bt3h, bt3l, b3,
                                              out, nullptr, nullptr, NCLS);
}